// Round 1
// baseline (455.801 us; speedup 1.0000x reference)
//
#include <hip/hip_runtime.h>
#include <hip/hip_bf16.h>

typedef __attribute__((ext_vector_type(8))) short bf16x8;
typedef __attribute__((ext_vector_type(4))) float f32x4;

#define B_SZ   4096
#define K1     25
#define K2     10
#define M_L1   45056   /* B*(1+K2) */
#define D      256
#define K_DIM  512

static __device__ __forceinline__ unsigned short f2bf(float f) {
    union { float f; unsigned u; } v; v.f = f;
    return (unsigned short)((v.u + 0x7fffu + ((v.u >> 16) & 1u)) >> 16);
}
static __device__ __forceinline__ float bf2f(unsigned short h) {
    union { unsigned u; float f; } v; v.u = ((unsigned)h) << 16;
    return v.f;
}

// ---- convert W1/W2 fp32 -> bf16 (131072 elements each) ----
__global__ __launch_bounds__(256)
void convert_w(const float* __restrict__ W1, const float* __restrict__ W2,
               unsigned short* __restrict__ W1b, unsigned short* __restrict__ W2b) {
    const int i = blockIdx.x * 256 + threadIdx.x;
    W1b[i] = f2bf(W1[i]);
    W2b[i] = f2bf(W2[i]);
}

// ---- layer-1 gather + mean: X1[m] = [ feat[l1_nodes[m]] | mean_k feat[neigh1[m,k]] ] (bf16) ----
__global__ __launch_bounds__(256)
void agg1_kernel(const float* __restrict__ feat,
                 const int* __restrict__ nodes_batch,
                 const int* __restrict__ neigh2,
                 const int* __restrict__ neigh1,
                 unsigned short* __restrict__ X1) {
    const int wave = threadIdx.x >> 6;
    const int lane = threadIdx.x & 63;
    const int m = (blockIdx.x << 2) + wave;   // one wave per row
    const int self_node = (m < B_SZ) ? nodes_batch[m] : neigh2[m - B_SZ];
    const float4 s = *(const float4*)(feat + (size_t)self_node * D + (lane << 2));
    float sx = 0.f, sy = 0.f, sz = 0.f, sw = 0.f;
    const int* nb = neigh1 + (size_t)m * K1;
    #pragma unroll
    for (int k = 0; k < K1; ++k) {
        const float4 v = *(const float4*)(feat + (size_t)nb[k] * D + (lane << 2));
        sx += v.x; sy += v.y; sz += v.z; sw += v.w;
    }
    const float inv = 1.0f / (float)K1;
    unsigned short* xr = X1 + (size_t)m * K_DIM;
    *(ushort4*)(xr + (lane << 2)) = make_ushort4(f2bf(s.x), f2bf(s.y), f2bf(s.z), f2bf(s.w));
    *(ushort4*)(xr + D + (lane << 2)) =
        make_ushort4(f2bf(sx * inv), f2bf(sy * inv), f2bf(sz * inv), f2bf(sw * inv));
}

// ---- layer-2 build: X2[b] = [ h1[b] | mean_k h1[B + b*K2 + k] ] (bf16) ----
__global__ __launch_bounds__(256)
void agg2_kernel(const unsigned short* __restrict__ h1,
                 unsigned short* __restrict__ X2) {
    const int wave = threadIdx.x >> 6;
    const int lane = threadIdx.x & 63;
    const int b = (blockIdx.x << 2) + wave;
    const ushort4 s = *(const ushort4*)(h1 + (size_t)b * D + (lane << 2));
    float sx = 0.f, sy = 0.f, sz = 0.f, sw = 0.f;
    #pragma unroll
    for (int k = 0; k < K2; ++k) {
        const ushort4 v = *(const ushort4*)(h1 + (size_t)(B_SZ + b * K2 + k) * D + (lane << 2));
        sx += bf2f(v.x); sy += bf2f(v.y); sz += bf2f(v.z); sw += bf2f(v.w);
    }
    const float inv = 1.0f / (float)K2;
    unsigned short* xr = X2 + (size_t)b * K_DIM;
    *(ushort4*)(xr + (lane << 2)) = s;
    *(ushort4*)(xr + D + (lane << 2)) =
        make_ushort4(f2bf(sx * inv), f2bf(sy * inv), f2bf(sz * inv), f2bf(sw * inv));
}

// ---- C[M,256] = relu(A[M,512] @ W[256,512]^T), bf16 in, bf16 or fp32 out ----
// grid: (M/128, 2), 256 threads (4 waves), wave = 64x64 via 4x4 of 16x16x32 MFMA
template<bool OUT_BF16>
__global__ __launch_bounds__(256)
void gemm_relu(const unsigned short* __restrict__ A,
               const unsigned short* __restrict__ W,
               void* __restrict__ Cout) {
    constexpr int LDA = 40;   // 128x32 tile, row padded 32->40 elems (80B): 2-way bank alias only
    __shared__ unsigned short As[128 * LDA];
    __shared__ unsigned short Bs[128 * LDA];
    const int tid  = threadIdx.x;
    const int wave = tid >> 6, lane = tid & 63;
    const int quad = lane >> 4, l16 = lane & 15;
    const int wm = (wave >> 1) << 6;       // wave's 64-row offset
    const int wn = (wave & 1) << 6;        // wave's 64-col offset
    const size_t row0 = (size_t)blockIdx.x * 128;
    const size_t col0 = (size_t)blockIdx.y * 128;
    const int r0 = tid >> 2;               // staging row 0..63
    const int c0 = (tid & 3) << 3;         // staging col {0,8,16,24}

    f32x4 acc[4][4];
    #pragma unroll
    for (int i = 0; i < 4; ++i)
        #pragma unroll
        for (int j = 0; j < 4; ++j)
            acc[i][j] = (f32x4){0.f, 0.f, 0.f, 0.f};

    const unsigned short* aBase = A + (row0 + r0) * K_DIM + c0;
    const unsigned short* wBase = W + (col0 + r0) * K_DIM + c0;

    for (int k0 = 0; k0 < K_DIM; k0 += 32) {
        __syncthreads();
        *(uint4*)&As[r0 * LDA + c0]        = *(const uint4*)(aBase + k0);
        *(uint4*)&As[(64 + r0) * LDA + c0] = *(const uint4*)(aBase + (size_t)64 * K_DIM + k0);
        *(uint4*)&Bs[r0 * LDA + c0]        = *(const uint4*)(wBase + k0);
        *(uint4*)&Bs[(64 + r0) * LDA + c0] = *(const uint4*)(wBase + (size_t)64 * K_DIM + k0);
        __syncthreads();
        bf16x8 af[4], bfr[4];
        #pragma unroll
        for (int i = 0; i < 4; ++i)
            af[i] = *(const bf16x8*)&As[(wm + i * 16 + l16) * LDA + quad * 8];
        #pragma unroll
        for (int i = 0; i < 4; ++i)
            bfr[i] = *(const bf16x8*)&Bs[(wn + i * 16 + l16) * LDA + quad * 8];
        #pragma unroll
        for (int mi = 0; mi < 4; ++mi)
            #pragma unroll
            for (int ni = 0; ni < 4; ++ni)
                acc[mi][ni] = __builtin_amdgcn_mfma_f32_16x16x32_bf16(
                    af[mi], bfr[ni], acc[mi][ni], 0, 0, 0);
    }

    #pragma unroll
    for (int mi = 0; mi < 4; ++mi) {
        #pragma unroll
        for (int ni = 0; ni < 4; ++ni) {
            #pragma unroll
            for (int r = 0; r < 4; ++r) {
                const size_t gm = row0 + wm + mi * 16 + quad * 4 + r;
                const size_t gn = col0 + wn + ni * 16 + l16;
                float v = acc[mi][ni][r];
                v = v > 0.f ? v : 0.f;
                if (OUT_BF16)
                    ((unsigned short*)Cout)[gm * D + gn] = f2bf(v);
                else
                    ((float*)Cout)[gm * D + gn] = v;
            }
        }
    }
}

extern "C" void kernel_launch(void* const* d_in, const int* in_sizes, int n_in,
                              void* d_out, int out_size, void* d_ws, size_t ws_size,
                              hipStream_t stream) {
    const float* feat        = (const float*)d_in[0];
    const float* W1          = (const float*)d_in[1];
    const float* W2          = (const float*)d_in[2];
    const int*   nodes_batch = (const int*)d_in[3];
    const int*   neigh2      = (const int*)d_in[4];
    const int*   neigh1      = (const int*)d_in[5];
    float* out = (float*)d_out;

    char* ws = (char*)d_ws;
    unsigned short* W1b = (unsigned short*)(ws);                      // 262144 B
    unsigned short* W2b = (unsigned short*)(ws + 262144);             // 262144 B
    unsigned short* X1  = (unsigned short*)(ws + 524288);             // 45056*512*2 = 46137344 B
    unsigned short* h1  = (unsigned short*)(ws + 524288 + 46137344);  // 45056*256*2 = 23068672 B
    unsigned short* X2  = (unsigned short*)(ws + 524288 + 46137344 + 23068672); // 4096*512*2 B

    convert_w<<<512, 256, 0, stream>>>(W1, W2, W1b, W2b);
    agg1_kernel<<<M_L1 / 4, 256, 0, stream>>>(feat, nodes_batch, neigh2, neigh1, X1);
    gemm_relu<true><<<dim3(M_L1 / 128, 2), 256, 0, stream>>>(X1, W1b, h1);
    agg2_kernel<<<B_SZ / 4, 256, 0, stream>>>(h1, X2);
    gemm_relu<false><<<dim3(B_SZ / 128, 2), 256, 0, stream>>>(X2, W2b, out);
}

// Round 2
// 422.247 us; speedup vs baseline: 1.0795x; 1.0795x over previous
//
#include <hip/hip_runtime.h>
#include <hip/hip_bf16.h>

typedef __attribute__((ext_vector_type(8))) short bf16x8;
typedef __attribute__((ext_vector_type(4))) float f32x4;

#define B_SZ   4096
#define K1     25
#define K2     10
#define M_L1   45056   /* B*(1+K2) */
#define D      256
#define K_DIM  512
#define N_NODES 200000

static __device__ __forceinline__ unsigned short f2bf(float f) {
    union { float f; unsigned u; } v; v.f = f;
    return (unsigned short)((v.u + 0x7fffu + ((v.u >> 16) & 1u)) >> 16);
}
static __device__ __forceinline__ float bf2f(unsigned short h) {
    union { unsigned u; float f; } v; v.u = ((unsigned)h) << 16;
    return v.f;
}
static __device__ __forceinline__ float bfhi(unsigned u) {     // high bf16 of packed pair
    union { unsigned u; float f; } v; v.u = u & 0xffff0000u;
    return v.f;
}
static __device__ __forceinline__ float bflo(unsigned u) {     // low bf16 of packed pair
    union { unsigned u; float f; } v; v.u = u << 16;
    return v.f;
}

// ---- convert features fp32 -> bf16 (51.2M elems), streaming ----
__global__ __launch_bounds__(256)
void convert_feat(const float* __restrict__ f, unsigned short* __restrict__ fb) {
    const size_t i = ((size_t)blockIdx.x * 256 + threadIdx.x) * 8;
    const float4 a = *(const float4*)(f + i);
    const float4 b = *(const float4*)(f + i + 4);
    ushort4 r0 = make_ushort4(f2bf(a.x), f2bf(a.y), f2bf(a.z), f2bf(a.w));
    ushort4 r1 = make_ushort4(f2bf(b.x), f2bf(b.y), f2bf(b.z), f2bf(b.w));
    *(ushort4*)(fb + i) = r0;
    *(ushort4*)(fb + i + 4) = r1;
}

// ---- convert W1/W2 fp32 -> bf16 (131072 elements each) ----
__global__ __launch_bounds__(256)
void convert_w(const float* __restrict__ W1, const float* __restrict__ W2,
               unsigned short* __restrict__ W1b, unsigned short* __restrict__ W2b) {
    const int i = blockIdx.x * 256 + threadIdx.x;
    W1b[i] = f2bf(W1[i]);
    W2b[i] = f2bf(W2[i]);
}

// ---- layer-1 gather + mean from bf16 table, max-MLP version ----
// One wave per output row. Wave halves: 32 lanes x 16B cover one 512B row.
// 13 iterations: j<12 -> (neigh 2j, neigh 2j+1); j==12 -> (neigh 24, self).
__global__ __launch_bounds__(256)
void agg1_kernel(const unsigned short* __restrict__ featb,
                 const int* __restrict__ nodes_batch,
                 const int* __restrict__ neigh2,
                 const int* __restrict__ neigh1,
                 unsigned short* __restrict__ X1) {
    const int wave = threadIdx.x >> 6;
    const int lane = threadIdx.x & 63;
    const int half = lane >> 5;
    const int sl   = lane & 31;
    const int m = (blockIdx.x << 2) + wave;
    const int self_node = (m < B_SZ) ? nodes_batch[m] : neigh2[m - B_SZ];
    const int* nb = neigh1 + (size_t)m * K1;
    const int e = sl << 3;                 // element offset within row (8 bf16 / 16B)

    uint4 v[13];
    #pragma unroll
    for (int j = 0; j < 13; ++j) {
        const int node = (j < 12) ? nb[2 * j + half]
                                  : (half ? self_node : nb[24]);
        v[j] = *(const uint4*)(featb + (size_t)node * D + e);
    }

    float acc[8] = {0.f, 0.f, 0.f, 0.f, 0.f, 0.f, 0.f, 0.f};
    #pragma unroll
    for (int j = 0; j < 12; ++j) {
        acc[0] += bflo(v[j].x); acc[1] += bfhi(v[j].x);
        acc[2] += bflo(v[j].y); acc[3] += bfhi(v[j].y);
        acc[4] += bflo(v[j].z); acc[5] += bfhi(v[j].z);
        acc[6] += bflo(v[j].w); acc[7] += bfhi(v[j].w);
    }
    if (half == 0) {  // slot (12,0) = neighbor 24; slot (12,1) = self (not averaged)
        acc[0] += bflo(v[12].x); acc[1] += bfhi(v[12].x);
        acc[2] += bflo(v[12].y); acc[3] += bfhi(v[12].y);
        acc[4] += bflo(v[12].z); acc[5] += bfhi(v[12].z);
        acc[6] += bflo(v[12].w); acc[7] += bfhi(v[12].w);
    }
    // cross-half combine: lower lanes pull upper half's partial sums
    #pragma unroll
    for (int i = 0; i < 8; ++i)
        acc[i] += __shfl(acc[i], sl + 32);

    unsigned short* xr = X1 + (size_t)m * K_DIM;
    if (half == 0) {
        const float inv = 1.0f / (float)K1;
        ushort4 p0 = make_ushort4(f2bf(acc[0] * inv), f2bf(acc[1] * inv),
                                  f2bf(acc[2] * inv), f2bf(acc[3] * inv));
        ushort4 p1 = make_ushort4(f2bf(acc[4] * inv), f2bf(acc[5] * inv),
                                  f2bf(acc[6] * inv), f2bf(acc[7] * inv));
        *(ushort4*)(xr + D + e) = p0;
        *(ushort4*)(xr + D + e + 4) = p1;
    } else {
        *(uint4*)(xr + e) = v[12];         // raw bf16 self-row copy
    }
}

// ---- layer-2 build: X2[b] = [ h1[b] | mean_k h1[B + b*K2 + k] ] (bf16) ----
__global__ __launch_bounds__(256)
void agg2_kernel(const unsigned short* __restrict__ h1,
                 unsigned short* __restrict__ X2) {
    const int wave = threadIdx.x >> 6;
    const int lane = threadIdx.x & 63;
    const int b = (blockIdx.x << 2) + wave;
    const ushort4 s = *(const ushort4*)(h1 + (size_t)b * D + (lane << 2));
    float sx = 0.f, sy = 0.f, sz = 0.f, sw = 0.f;
    #pragma unroll
    for (int k = 0; k < K2; ++k) {
        const ushort4 v = *(const ushort4*)(h1 + (size_t)(B_SZ + b * K2 + k) * D + (lane << 2));
        sx += bf2f(v.x); sy += bf2f(v.y); sz += bf2f(v.z); sw += bf2f(v.w);
    }
    const float inv = 1.0f / (float)K2;
    unsigned short* xr = X2 + (size_t)b * K_DIM;
    *(ushort4*)(xr + (lane << 2)) = s;
    *(ushort4*)(xr + D + (lane << 2)) =
        make_ushort4(f2bf(sx * inv), f2bf(sy * inv), f2bf(sz * inv), f2bf(sw * inv));
}

// ---- C[M,256] = relu(A[M,512] @ W[256,512]^T), bf16 in, bf16 or fp32 out ----
template<bool OUT_BF16>
__global__ __launch_bounds__(256)
void gemm_relu(const unsigned short* __restrict__ A,
               const unsigned short* __restrict__ W,
               void* __restrict__ Cout) {
    constexpr int LDA = 40;   // 128x32 tile, row padded 32->40 elems (80B): 2-way bank alias only
    __shared__ unsigned short As[128 * LDA];
    __shared__ unsigned short Bs[128 * LDA];
    const int tid  = threadIdx.x;
    const int wave = tid >> 6, lane = tid & 63;
    const int quad = lane >> 4, l16 = lane & 15;
    const int wm = (wave >> 1) << 6;
    const int wn = (wave & 1) << 6;
    const size_t row0 = (size_t)blockIdx.x * 128;
    const size_t col0 = (size_t)blockIdx.y * 128;
    const int r0 = tid >> 2;
    const int c0 = (tid & 3) << 3;

    f32x4 acc[4][4];
    #pragma unroll
    for (int i = 0; i < 4; ++i)
        #pragma unroll
        for (int j = 0; j < 4; ++j)
            acc[i][j] = (f32x4){0.f, 0.f, 0.f, 0.f};

    const unsigned short* aBase = A + (row0 + r0) * K_DIM + c0;
    const unsigned short* wBase = W + (col0 + r0) * K_DIM + c0;

    for (int k0 = 0; k0 < K_DIM; k0 += 32) {
        __syncthreads();
        *(uint4*)&As[r0 * LDA + c0]        = *(const uint4*)(aBase + k0);
        *(uint4*)&As[(64 + r0) * LDA + c0] = *(const uint4*)(aBase + (size_t)64 * K_DIM + k0);
        *(uint4*)&Bs[r0 * LDA + c0]        = *(const uint4*)(wBase + k0);
        *(uint4*)&Bs[(64 + r0) * LDA + c0] = *(const uint4*)(wBase + (size_t)64 * K_DIM + k0);
        __syncthreads();
        bf16x8 af[4], bfr[4];
        #pragma unroll
        for (int i = 0; i < 4; ++i)
            af[i] = *(const bf16x8*)&As[(wm + i * 16 + l16) * LDA + quad * 8];
        #pragma unroll
        for (int i = 0; i < 4; ++i)
            bfr[i] = *(const bf16x8*)&Bs[(wn + i * 16 + l16) * LDA + quad * 8];
        #pragma unroll
        for (int mi = 0; mi < 4; ++mi)
            #pragma unroll
            for (int ni = 0; ni < 4; ++ni)
                acc[mi][ni] = __builtin_amdgcn_mfma_f32_16x16x32_bf16(
                    af[mi], bfr[ni], acc[mi][ni], 0, 0, 0);
    }

    #pragma unroll
    for (int mi = 0; mi < 4; ++mi) {
        #pragma unroll
        for (int ni = 0; ni < 4; ++ni) {
            #pragma unroll
            for (int r = 0; r < 4; ++r) {
                const size_t gm = row0 + wm + mi * 16 + quad * 4 + r;
                const size_t gn = col0 + wn + ni * 16 + l16;
                float v = acc[mi][ni][r];
                v = v > 0.f ? v : 0.f;
                if (OUT_BF16)
                    ((unsigned short*)Cout)[gm * D + gn] = f2bf(v);
                else
                    ((float*)Cout)[gm * D + gn] = v;
            }
        }
    }
}

extern "C" void kernel_launch(void* const* d_in, const int* in_sizes, int n_in,
                              void* d_out, int out_size, void* d_ws, size_t ws_size,
                              hipStream_t stream) {
    const float* feat        = (const float*)d_in[0];
    const float* W1          = (const float*)d_in[1];
    const float* W2          = (const float*)d_in[2];
    const int*   nodes_batch = (const int*)d_in[3];
    const int*   neigh2      = (const int*)d_in[4];
    const int*   neigh1      = (const int*)d_in[5];
    float* out = (float*)d_out;

    char* ws = (char*)d_ws;
    // Region A: featb (102,400,000 B). Dead after agg1 -> h1/X2 alias into it.
    unsigned short* featb = (unsigned short*)(ws);
    unsigned short* h1    = (unsigned short*)(ws);                      // alias (after agg1)
    unsigned short* X2    = (unsigned short*)(ws + 23068672);           // alias (after agg1)
    unsigned short* X1    = (unsigned short*)(ws + 102400000);          // 46,137,344 B
    unsigned short* W1b   = (unsigned short*)(ws + 102400000 + 46137344);
    unsigned short* W2b   = (unsigned short*)(ws + 102400000 + 46137344 + 262144);

    convert_feat<<<25000, 256, 0, stream>>>(feat, featb);
    convert_w<<<512, 256, 0, stream>>>(W1, W2, W1b, W2b);
    agg1_kernel<<<M_L1 / 4, 256, 0, stream>>>(featb, nodes_batch, neigh2, neigh1, X1);
    gemm_relu<true><<<dim3(M_L1 / 128, 2), 256, 0, stream>>>(X1, W1b, h1);
    agg2_kernel<<<B_SZ / 4, 256, 0, stream>>>(h1, X2);
    gemm_relu<false><<<dim3(B_SZ / 128, 2), 256, 0, stream>>>(X2, W2b, out);
}

// Round 3
// 381.385 us; speedup vs baseline: 1.1951x; 1.1071x over previous
//
#include <hip/hip_runtime.h>
#include <hip/hip_bf16.h>

typedef __attribute__((ext_vector_type(8))) short bf16x8;
typedef __attribute__((ext_vector_type(4))) float f32x4;
typedef __attribute__((ext_vector_type(2))) float f32x2;

#define B_SZ   4096
#define K1     25
#define K2     10
#define M_L1   45056   /* B*(1+K2) */
#define D      256
#define K_DIM  512
#define N_NODES 200000

static __device__ __forceinline__ unsigned short f2bf(float f) {
    union { float f; unsigned u; } v; v.f = f;
    return (unsigned short)((v.u + 0x7fffu + ((v.u >> 16) & 1u)) >> 16);
}
static __device__ __forceinline__ float bf2f(unsigned short h) {
    union { unsigned u; float f; } v; v.u = ((unsigned)h) << 16;
    return v.f;
}

// ---- convert features fp32 -> fp8 e4m3 (51.2M elems), streaming ----
// 8 elems/thread: read 2x float4 (32B), write uint2 (8B)
__global__ __launch_bounds__(256)
void convert_fp8(const float* __restrict__ f, unsigned* __restrict__ f8) {
    const size_t i = ((size_t)blockIdx.x * 256 + threadIdx.x) * 8;
    const float4 a = *(const float4*)(f + i);
    const float4 b = *(const float4*)(f + i + 4);
    unsigned u0 = 0, u1 = 0;
    u0 = __builtin_amdgcn_cvt_pk_fp8_f32(a.x, a.y, u0, false);
    u0 = __builtin_amdgcn_cvt_pk_fp8_f32(a.z, a.w, u0, true);
    u1 = __builtin_amdgcn_cvt_pk_fp8_f32(b.x, b.y, u1, false);
    u1 = __builtin_amdgcn_cvt_pk_fp8_f32(b.z, b.w, u1, true);
    uint2 r; r.x = u0; r.y = u1;
    *(uint2*)(f8 + (i >> 2)) = r;
}

// ---- convert W1/W2 fp32 -> bf16 (131072 elements each) ----
__global__ __launch_bounds__(256)
void convert_w(const float* __restrict__ W1, const float* __restrict__ W2,
               unsigned short* __restrict__ W1b, unsigned short* __restrict__ W2b) {
    const int i = blockIdx.x * 256 + threadIdx.x;
    W1b[i] = f2bf(W1[i]);
    W2b[i] = f2bf(W2[i]);
}

// ---- layer-1 gather + mean: agg from fp8 table (256B/row, 4B/lane),
//      self from fp32 features (1KB/row, 16B/lane). One wave per output row. ----
__global__ __launch_bounds__(256)
void agg1_kernel(const float* __restrict__ feat,
                 const unsigned* __restrict__ f8,     // fp8 table as uints (4 vals each)
                 const int* __restrict__ nodes_batch,
                 const int* __restrict__ neigh2,
                 const int* __restrict__ neigh1,
                 unsigned short* __restrict__ X1) {
    const int wave = threadIdx.x >> 6;
    const int lane = threadIdx.x & 63;
    const int m = (blockIdx.x << 2) + wave;
    const int self_node = (m < B_SZ) ? nodes_batch[m] : neigh2[m - B_SZ];
    const int* nb = neigh1 + (size_t)m * K1;

    // prefetch all 25 neighbor indices: one coalesced load + shuffle broadcast
    int idxv = (lane < K1) ? nb[lane] : 0;

    // self row: 64 lanes x float4 = 1KB fp32 row
    const float4 s = *(const float4*)(feat + (size_t)self_node * D + (lane << 2));

    // agg rows: 64 lanes x uint (4 fp8) = 256B row; hold all 25 in flight
    unsigned q[K1];
    #pragma unroll
    for (int j = 0; j < K1; ++j) {
        const int node = __shfl(idxv, j);
        q[j] = f8[(size_t)node * (D / 4) + lane];
    }

    float a0 = 0.f, a1 = 0.f, a2 = 0.f, a3 = 0.f;
    #pragma unroll
    for (int j = 0; j < K1; ++j) {
        const f32x2 lo = __builtin_amdgcn_cvt_pk_f32_fp8(q[j], false);
        const f32x2 hi = __builtin_amdgcn_cvt_pk_f32_fp8(q[j], true);
        a0 += lo.x; a1 += lo.y; a2 += hi.x; a3 += hi.y;
    }
    const float inv = 1.0f / (float)K1;

    unsigned short* xr = X1 + (size_t)m * K_DIM;
    *(ushort4*)(xr + (lane << 2)) =
        make_ushort4(f2bf(s.x), f2bf(s.y), f2bf(s.z), f2bf(s.w));
    *(ushort4*)(xr + D + (lane << 2)) =
        make_ushort4(f2bf(a0 * inv), f2bf(a1 * inv), f2bf(a2 * inv), f2bf(a3 * inv));
}

// ---- layer-2 build: X2[b] = [ h1[b] | mean_k h1[B + b*K2 + k] ] (bf16) ----
__global__ __launch_bounds__(256)
void agg2_kernel(const unsigned short* __restrict__ h1,
                 unsigned short* __restrict__ X2) {
    const int wave = threadIdx.x >> 6;
    const int lane = threadIdx.x & 63;
    const int b = (blockIdx.x << 2) + wave;
    const ushort4 s = *(const ushort4*)(h1 + (size_t)b * D + (lane << 2));
    float sx = 0.f, sy = 0.f, sz = 0.f, sw = 0.f;
    #pragma unroll
    for (int k = 0; k < K2; ++k) {
        const ushort4 v = *(const ushort4*)(h1 + (size_t)(B_SZ + b * K2 + k) * D + (lane << 2));
        sx += bf2f(v.x); sy += bf2f(v.y); sz += bf2f(v.z); sw += bf2f(v.w);
    }
    const float inv = 1.0f / (float)K2;
    unsigned short* xr = X2 + (size_t)b * K_DIM;
    *(ushort4*)(xr + (lane << 2)) = s;
    *(ushort4*)(xr + D + (lane << 2)) =
        make_ushort4(f2bf(sx * inv), f2bf(sy * inv), f2bf(sz * inv), f2bf(sw * inv));
}

// ---- C[M,256] = relu(A[M,512] @ W[256,512]^T), bf16 in, bf16 or fp32 out ----
template<bool OUT_BF16>
__global__ __launch_bounds__(256)
void gemm_relu(const unsigned short* __restrict__ A,
               const unsigned short* __restrict__ W,
               void* __restrict__ Cout) {
    constexpr int LDA = 40;   // 128x32 tile, row padded 32->40 elems (80B): 2-way bank alias only
    __shared__ unsigned short As[128 * LDA];
    __shared__ unsigned short Bs[128 * LDA];
    const int tid  = threadIdx.x;
    const int wave = tid >> 6, lane = tid & 63;
    const int quad = lane >> 4, l16 = lane & 15;
    const int wm = (wave >> 1) << 6;
    const int wn = (wave & 1) << 6;
    const size_t row0 = (size_t)blockIdx.x * 128;
    const size_t col0 = (size_t)blockIdx.y * 128;
    const int r0 = tid >> 2;
    const int c0 = (tid & 3) << 3;

    f32x4 acc[4][4];
    #pragma unroll
    for (int i = 0; i < 4; ++i)
        #pragma unroll
        for (int j = 0; j < 4; ++j)
            acc[i][j] = (f32x4){0.f, 0.f, 0.f, 0.f};

    const unsigned short* aBase = A + (row0 + r0) * K_DIM + c0;
    const unsigned short* wBase = W + (col0 + r0) * K_DIM + c0;

    for (int k0 = 0; k0 < K_DIM; k0 += 32) {
        __syncthreads();
        *(uint4*)&As[r0 * LDA + c0]        = *(const uint4*)(aBase + k0);
        *(uint4*)&As[(64 + r0) * LDA + c0] = *(const uint4*)(aBase + (size_t)64 * K_DIM + k0);
        *(uint4*)&Bs[r0 * LDA + c0]        = *(const uint4*)(wBase + k0);
        *(uint4*)&Bs[(64 + r0) * LDA + c0] = *(const uint4*)(wBase + (size_t)64 * K_DIM + k0);
        __syncthreads();
        bf16x8 af[4], bfr[4];
        #pragma unroll
        for (int i = 0; i < 4; ++i)
            af[i] = *(const bf16x8*)&As[(wm + i * 16 + l16) * LDA + quad * 8];
        #pragma unroll
        for (int i = 0; i < 4; ++i)
            bfr[i] = *(const bf16x8*)&Bs[(wn + i * 16 + l16) * LDA + quad * 8];
        #pragma unroll
        for (int mi = 0; mi < 4; ++mi)
            #pragma unroll
            for (int ni = 0; ni < 4; ++ni)
                acc[mi][ni] = __builtin_amdgcn_mfma_f32_16x16x32_bf16(
                    af[mi], bfr[ni], acc[mi][ni], 0, 0, 0);
    }

    #pragma unroll
    for (int mi = 0; mi < 4; ++mi) {
        #pragma unroll
        for (int ni = 0; ni < 4; ++ni) {
            #pragma unroll
            for (int r = 0; r < 4; ++r) {
                const size_t gm = row0 + wm + mi * 16 + quad * 4 + r;
                const size_t gn = col0 + wn + ni * 16 + l16;
                float v = acc[mi][ni][r];
                v = v > 0.f ? v : 0.f;
                if (OUT_BF16)
                    ((unsigned short*)Cout)[gm * D + gn] = f2bf(v);
                else
                    ((float*)Cout)[gm * D + gn] = v;
            }
        }
    }
}

extern "C" void kernel_launch(void* const* d_in, const int* in_sizes, int n_in,
                              void* d_out, int out_size, void* d_ws, size_t ws_size,
                              hipStream_t stream) {
    const float* feat        = (const float*)d_in[0];
    const float* W1          = (const float*)d_in[1];
    const float* W2          = (const float*)d_in[2];
    const int*   nodes_batch = (const int*)d_in[3];
    const int*   neigh2      = (const int*)d_in[4];
    const int*   neigh1      = (const int*)d_in[5];
    float* out = (float*)d_out;

    char* ws = (char*)d_ws;
    unsigned*       f8   = (unsigned*)(ws);                              // 51,200,000 B
    unsigned short* X1   = (unsigned short*)(ws + 51200000);             // 46,137,344 B
    unsigned short* h1   = (unsigned short*)(ws + 51200000 + 46137344);  // 23,068,672 B
    unsigned short* X2   = (unsigned short*)(ws + 51200000 + 46137344 + 23068672); // 4,194,304 B
    unsigned short* W1b  = (unsigned short*)(ws + 51200000 + 46137344 + 23068672 + 4194304);
    unsigned short* W2b  = (unsigned short*)(ws + 51200000 + 46137344 + 23068672 + 4194304 + 262144);

    convert_fp8<<<25000, 256, 0, stream>>>(feat, f8);
    convert_w<<<512, 256, 0, stream>>>(W1, W2, W1b, W2b);
    agg1_kernel<<<M_L1 / 4, 256, 0, stream>>>(feat, f8, nodes_batch, neigh2, neigh1, X1);
    gemm_relu<true><<<dim3(M_L1 / 128, 2), 256, 0, stream>>>(X1, W1b, h1);
    agg2_kernel<<<B_SZ / 4, 256, 0, stream>>>(h1, X2);
    gemm_relu<false><<<dim3(B_SZ / 128, 2), 256, 0, stream>>>(X2, W2b, out);
}

// Round 4
// 378.485 us; speedup vs baseline: 1.2043x; 1.0077x over previous
//
#include <hip/hip_runtime.h>
#include <hip/hip_bf16.h>

typedef __attribute__((ext_vector_type(8))) short bf16x8;
typedef __attribute__((ext_vector_type(4))) float f32x4;
typedef __attribute__((ext_vector_type(2))) float f32x2;

#define B_SZ   4096
#define K1     25
#define K2     10
#define M_L1   45056   /* B*(1+K2) */
#define D      256
#define K_DIM  512
#define N_NODES 200000

static __device__ __forceinline__ unsigned short f2bf(float f) {
    union { float f; unsigned u; } v; v.f = f;
    return (unsigned short)((v.u + 0x7fffu + ((v.u >> 16) & 1u)) >> 16);
}
static __device__ __forceinline__ float bf2f(unsigned short h) {
    union { unsigned u; float f; } v; v.u = ((unsigned)h) << 16;
    return v.f;
}

// ---- convert features fp32 -> fp8 e4m3 (51.2M elems), streaming ----
__global__ __launch_bounds__(256)
void convert_fp8(const float* __restrict__ f, unsigned* __restrict__ f8) {
    const size_t i = ((size_t)blockIdx.x * 256 + threadIdx.x) * 8;
    const float4 a = *(const float4*)(f + i);
    const float4 b = *(const float4*)(f + i + 4);
    unsigned u0 = 0, u1 = 0;
    u0 = __builtin_amdgcn_cvt_pk_fp8_f32(a.x, a.y, u0, false);
    u0 = __builtin_amdgcn_cvt_pk_fp8_f32(a.z, a.w, u0, true);
    u1 = __builtin_amdgcn_cvt_pk_fp8_f32(b.x, b.y, u1, false);
    u1 = __builtin_amdgcn_cvt_pk_fp8_f32(b.z, b.w, u1, true);
    uint2 r; r.x = u0; r.y = u1;
    *(uint2*)(f8 + (i >> 2)) = r;
}

// ---- convert W1/W2 fp32 -> bf16 (131072 elements each) ----
__global__ __launch_bounds__(256)
void convert_w(const float* __restrict__ W1, const float* __restrict__ W2,
               unsigned short* __restrict__ W1b, unsigned short* __restrict__ W2b) {
    const int i = blockIdx.x * 256 + threadIdx.x;
    W1b[i] = f2bf(W1[i]);
    W2b[i] = f2bf(W2[i]);
}

// ---- layer-1 gather + mean: agg from fp8 table, self from fp32 features ----
__global__ __launch_bounds__(256)
void agg1_kernel(const float* __restrict__ feat,
                 const unsigned* __restrict__ f8,
                 const int* __restrict__ nodes_batch,
                 const int* __restrict__ neigh2,
                 const int* __restrict__ neigh1,
                 unsigned short* __restrict__ X1) {
    const int wave = threadIdx.x >> 6;
    const int lane = threadIdx.x & 63;
    const int m = (blockIdx.x << 2) + wave;
    const int self_node = (m < B_SZ) ? nodes_batch[m] : neigh2[m - B_SZ];
    const int* nb = neigh1 + (size_t)m * K1;

    int idxv = (lane < K1) ? nb[lane] : 0;
    const float4 s = *(const float4*)(feat + (size_t)self_node * D + (lane << 2));

    unsigned q[K1];
    #pragma unroll
    for (int j = 0; j < K1; ++j) {
        const int node = __shfl(idxv, j);
        q[j] = f8[(size_t)node * (D / 4) + lane];
    }

    float a0 = 0.f, a1 = 0.f, a2 = 0.f, a3 = 0.f;
    #pragma unroll
    for (int j = 0; j < K1; ++j) {
        const f32x2 lo = __builtin_amdgcn_cvt_pk_f32_fp8(q[j], false);
        const f32x2 hi = __builtin_amdgcn_cvt_pk_f32_fp8(q[j], true);
        a0 += lo.x; a1 += lo.y; a2 += hi.x; a3 += hi.y;
    }
    const float inv = 1.0f / (float)K1;

    unsigned short* xr = X1 + (size_t)m * K_DIM;
    *(ushort4*)(xr + (lane << 2)) =
        make_ushort4(f2bf(s.x), f2bf(s.y), f2bf(s.z), f2bf(s.w));
    *(ushort4*)(xr + D + (lane << 2)) =
        make_ushort4(f2bf(a0 * inv), f2bf(a1 * inv), f2bf(a2 * inv), f2bf(a3 * inv));
}

// ---- layer-2 build: X2[b] = [ h1[b] | mean_k h1[B + b*K2 + k] ] (bf16) ----
__global__ __launch_bounds__(256)
void agg2_kernel(const unsigned short* __restrict__ h1,
                 unsigned short* __restrict__ X2) {
    const int wave = threadIdx.x >> 6;
    const int lane = threadIdx.x & 63;
    const int b = (blockIdx.x << 2) + wave;
    const ushort4 s = *(const ushort4*)(h1 + (size_t)b * D + (lane << 2));
    float sx = 0.f, sy = 0.f, sz = 0.f, sw = 0.f;
    #pragma unroll
    for (int k = 0; k < K2; ++k) {
        const ushort4 v = *(const ushort4*)(h1 + (size_t)(B_SZ + b * K2 + k) * D + (lane << 2));
        sx += bf2f(v.x); sy += bf2f(v.y); sz += bf2f(v.z); sw += bf2f(v.w);
    }
    const float inv = 1.0f / (float)K2;
    unsigned short* xr = X2 + (size_t)b * K_DIM;
    *(ushort4*)(xr + (lane << 2)) = s;
    *(ushort4*)(xr + D + (lane << 2)) =
        make_ushort4(f2bf(sx * inv), f2bf(sy * inv), f2bf(sz * inv), f2bf(sw * inv));
}

// ---- C[M,256] = relu(A[M,512] @ W[256,512]^T), m97-style K-loop ----
// BK=64, unpadded 128B LDS rows, width-16 global_load_lds staging.
// XOR swizzle: 16B chunk c of row r stored at slot c^(r&7) -> ds_read_b128
// fragment reads hit each 4-bank group with exactly 2 lanes (free, m136),
// while staging stays lane-contiguous in LDS (wave-uniform base + lane*16).
template<bool OUT_BF16>
__global__ __launch_bounds__(256)
void gemm_relu(const unsigned short* __restrict__ A,
               const unsigned short* __restrict__ W,
               void* __restrict__ Cout) {
    __shared__ unsigned short As[128 * 64];   // 16 KB
    __shared__ unsigned short Bs[128 * 64];   // 16 KB
    const int tid  = threadIdx.x;
    const int w    = tid >> 6, lane = tid & 63;
    const int quad = lane >> 4, l16 = lane & 15;
    const int wm = (w >> 1) << 6;
    const int wn = (w & 1) << 6;
    const size_t row0 = (size_t)blockIdx.x * 128;
    const size_t col0 = (size_t)blockIdx.y * 128;

    // staging: wave w call n covers LDS rows (w*4+n)*8 .. +7 (1024 B each)
    const int srow   = (w << 5) + (lane >> 3);            // + n*8 per call
    const int schunk = ((lane & 7) ^ (lane >> 3)) << 3;   // swizzled 16B chunk (elems)
    const unsigned short* aG = A + (row0 + srow) * K_DIM + schunk;
    const unsigned short* bG = W + (col0 + srow) * K_DIM + schunk;

    f32x4 acc[4][4];
    #pragma unroll
    for (int i = 0; i < 4; ++i)
        #pragma unroll
        for (int j = 0; j < 4; ++j)
            acc[i][j] = (f32x4){0.f, 0.f, 0.f, 0.f};

    for (int k0 = 0; k0 < K_DIM; k0 += 64) {
        __syncthreads();
        #pragma unroll
        for (int n = 0; n < 4; ++n) {
            __builtin_amdgcn_global_load_lds(
                (const __attribute__((address_space(1))) void*)(aG + (size_t)(n * 8) * K_DIM + k0),
                (__attribute__((address_space(3))) void*)(As + ((w << 2) + n) * 512),
                16, 0, 0);
            __builtin_amdgcn_global_load_lds(
                (const __attribute__((address_space(1))) void*)(bG + (size_t)(n * 8) * K_DIM + k0),
                (__attribute__((address_space(3))) void*)(Bs + ((w << 2) + n) * 512),
                16, 0, 0);
        }
        __syncthreads();
        #pragma unroll
        for (int ks = 0; ks < 2; ++ks) {
            bf16x8 af[4], bfr[4];
            #pragma unroll
            for (int i = 0; i < 4; ++i) {
                const int row = wm + i * 16 + l16;
                af[i] = *(const bf16x8*)&As[row * 64 + ((((ks << 2) + quad) ^ (l16 & 7)) << 3)];
            }
            #pragma unroll
            for (int i = 0; i < 4; ++i) {
                const int row = wn + i * 16 + l16;
                bfr[i] = *(const bf16x8*)&Bs[row * 64 + ((((ks << 2) + quad) ^ (l16 & 7)) << 3)];
            }
            #pragma unroll
            for (int mi = 0; mi < 4; ++mi)
                #pragma unroll
                for (int ni = 0; ni < 4; ++ni)
                    acc[mi][ni] = __builtin_amdgcn_mfma_f32_16x16x32_bf16(
                        af[mi], bfr[ni], acc[mi][ni], 0, 0, 0);
        }
    }

    #pragma unroll
    for (int mi = 0; mi < 4; ++mi) {
        #pragma unroll
        for (int ni = 0; ni < 4; ++ni) {
            #pragma unroll
            for (int r = 0; r < 4; ++r) {
                const size_t gm = row0 + wm + mi * 16 + quad * 4 + r;
                const size_t gn = col0 + wn + ni * 16 + l16;
                float v = acc[mi][ni][r];
                v = v > 0.f ? v : 0.f;
                if (OUT_BF16)
                    ((unsigned short*)Cout)[gm * D + gn] = f2bf(v);
                else
                    ((float*)Cout)[gm * D + gn] = v;
            }
        }
    }
}

extern "C" void kernel_launch(void* const* d_in, const int* in_sizes, int n_in,
                              void* d_out, int out_size, void* d_ws, size_t ws_size,
                              hipStream_t stream) {
    const float* feat        = (const float*)d_in[0];
    const float* W1          = (const float*)d_in[1];
    const float* W2          = (const float*)d_in[2];
    const int*   nodes_batch = (const int*)d_in[3];
    const int*   neigh2      = (const int*)d_in[4];
    const int*   neigh1      = (const int*)d_in[5];
    float* out = (float*)d_out;

    char* ws = (char*)d_ws;
    unsigned*       f8   = (unsigned*)(ws);                              // 51,200,000 B
    unsigned short* X1   = (unsigned short*)(ws + 51200000);             // 46,137,344 B
    unsigned short* h1   = (unsigned short*)(ws + 51200000 + 46137344);  // 23,068,672 B
    unsigned short* X2   = (unsigned short*)(ws + 51200000 + 46137344 + 23068672); // 4,194,304 B
    unsigned short* W1b  = (unsigned short*)(ws + 51200000 + 46137344 + 23068672 + 4194304);
    unsigned short* W2b  = (unsigned short*)(ws + 51200000 + 46137344 + 23068672 + 4194304 + 262144);

    convert_fp8<<<25000, 256, 0, stream>>>(feat, f8);
    convert_w<<<512, 256, 0, stream>>>(W1, W2, W1b, W2b);
    agg1_kernel<<<M_L1 / 4, 256, 0, stream>>>(feat, f8, nodes_batch, neigh2, neigh1, X1);
    gemm_relu<true><<<dim3(M_L1 / 128, 2), 256, 0, stream>>>(X1, W1b, h1);
    agg2_kernel<<<B_SZ / 4, 256, 0, stream>>>(h1, X2);
    gemm_relu<false><<<dim3(B_SZ / 128, 2), 256, 0, stream>>>(X2, W2b, out);
}